// Round 10
// baseline (17908.157 us; speedup 1.0000x reference)
//
#include <hip/hip_runtime.h>
#include <math.h>
#include <stdint.h>

typedef _Float16 f16;
typedef _Float16 f16x8 __attribute__((ext_vector_type(8)));
typedef float f32x16 __attribute__((ext_vector_type(16)));

#define BATCH 1024
#define HD    512
#define TST   100

// ---------------- access primitives ----------------
__device__ __forceinline__ float4 coh_ld_x4(const void* p) {
    float4 v;
    asm volatile("global_load_dwordx4 %0, %1, off sc0 sc1" : "=v"(v) : "v"(p) : "memory");
    return v;
}
__device__ __forceinline__ float4 ld_x4(const void* p) {
    float4 v;
    asm volatile("global_load_dwordx4 %0, %1, off" : "=v"(v) : "v"(p) : "memory");
    return v;
}
__device__ __forceinline__ void coh_store_u32(uint32_t* p, uint32_t v) {
    asm volatile("global_store_dword %0, %1, off sc0 sc1" :: "v"(p), "v"(v) : "memory");
}
__device__ __forceinline__ void coh_store_i32(int* p, int v) {
    asm volatile("global_store_dword %0, %1, off sc0 sc1" :: "v"(p), "v"(v) : "memory");
}
__device__ __forceinline__ int coh_load_i32(const int* p) {
    int v;
    asm volatile("global_load_dword %0, %1, off sc0 sc1\n\ts_waitcnt vmcnt(0)"
                 : "=v"(v) : "v"(p) : "memory");
    return v;
}
__device__ __forceinline__ void drain_vm() {
    asm volatile("s_waitcnt vmcnt(0)" ::: "memory");
    __builtin_amdgcn_sched_barrier(0);
}
__device__ __forceinline__ void wait_vm(int n) {   // n folds to constant after unroll
    switch (n) {
    case 0:  asm volatile("s_waitcnt vmcnt(0)"  ::: "memory"); break;
    case 4:  asm volatile("s_waitcnt vmcnt(4)"  ::: "memory"); break;
    case 6:  asm volatile("s_waitcnt vmcnt(6)"  ::: "memory"); break;
    case 8:  asm volatile("s_waitcnt vmcnt(8)"  ::: "memory"); break;
    default: asm volatile("s_waitcnt vmcnt(10)" ::: "memory"); break;
    }
    __builtin_amdgcn_sched_barrier(0);
}

// fast transcendentals (validated: R8/R9 absmax 1.5e-5 vs 1e-4 threshold)
__device__ __forceinline__ float fast_sig(float x) {
    return 1.0f / (1.0f + __expf(-x));
}
__device__ __forceinline__ float fast_tanh(float x) {
    float xc = fminf(fmaxf(x, -15.0f), 15.0f);
    float e = __expf(2.0f * xc);
    return 1.0f - 2.0f / (e + 1.0f);
}

// ---------------- setup kernels ----------------
// A-image for BM=512, direct-from-L2 fragment loads:
// per (mt 0..3, kt): 16 slots [s(2b)|p(1b)|half(1b)] x 512 rows x 16B = 128KB.
__global__ void split_w(const float* __restrict__ src0, int ksplit,
                        const float* __restrict__ src1, int NKT, f16* __restrict__ out)
{
    int c = blockIdx.x * 256 + threadIdx.x;
    int total = 4 * NKT * 8192;
    if (c >= total) return;
    int u = c & 8191;
    int t2 = c >> 13;            // mt*NKT + kt
    int kt = t2 % NKT;
    int mt = t2 / NKT;
    int inner = u >> 9;          // s*4 + p*2 + half
    int row = u & 511;
    int s = inner >> 2, p = (inner >> 1) & 1, half = inner & 1;
    int m = mt * 512 + row;
    int orow = (m & 3) * HD + (m >> 2);     // original row g*512+hl (rows permuted hl*4+g)
    int kb = kt * 64 + s * 16 + half * 8;
    f16 v[8];
    #pragma unroll
    for (int e = 0; e < 8; ++e) {
        int k = kb + e;
        float w = (k < ksplit) ? src0[(size_t)orow * ksplit + k]
                               : src1[(size_t)orow * HD + (k - ksplit)];
        float w32 = w * 32.0f;
        f16 hi = (f16)w32;
        v[e] = p ? (f16)((w32 - (float)hi) * 2048.0f) : hi;
    }
    *(f16x8*)(out + (size_t)c * 8) = *(f16x8*)v;
}

__global__ void prep_b4(const float* __restrict__ b, float* __restrict__ bt) {
    int c = blockIdx.x * 256 + threadIdx.x;     // c = hl*4+g
    if (c < 2048) bt[c] = b[(c & 3) * HD + (c >> 2)];
}

__global__ void prep_wih4(const float* __restrict__ W, float* __restrict__ o) {
    int c = blockIdx.x * 256 + threadIdx.x;     // c = hl*16 + g*4 + j
    if (c < 8192) {
        int j = c & 3, g = (c >> 2) & 3, hl = c >> 4;
        o[c] = W[(size_t)(g * HD + hl) * 4 + j];
    }
}

// ---------------- cross-block sync: per-block epoch cells (proven R7-R9) ----------------
__device__ __forceinline__ void publish(int* cell, int epoch) {
    drain_vm();
    __syncthreads();
    if (threadIdx.x == 0)
        coh_store_i32(cell, epoch);
}
__device__ __forceinline__ void wait2(const int* a, int ta, const int* b, int tb) {
    if (threadIdx.x < 64) {
        const int l = threadIdx.x & 3;            // 4 blocks per group
        const bool useB = (threadIdx.x & 4) != 0;
        const int* p = (useB ? b : a) + l * 16;
        const int tgt = useB ? tb : ta;
        for (;;) {
            int v = coh_load_i32(p);
            if (__all(v >= tgt)) break;
            __builtin_amdgcn_s_sleep(2);
        }
    }
    __syncthreads();
}

// ---------------- fused LSTM layer-step: BM=512 x BN=64, 8 waves ----------------
template<int NKT, bool RANK4>
__device__ __forceinline__ void layer_step(
    const f16* __restrict__ Wst, const f16* __restrict__ src1, const f16* __restrict__ src2,
    const float* __restrict__ wih4, const float* __restrict__ xin, int xstride,
    const float* __restrict__ bt4, float* __restrict__ cT, f16* __restrict__ hout,
    char* smem, int mt, int nt)
{
    const int tid  = threadIdx.x;
    const int lane = tid & 63;
    const int wv   = tid >> 6;        // wave 0..7 (M-stacked)
    const int col  = lane & 31;
    const int half = lane >> 5;       // k-octet
    const int xk   = col & 15;        // B LDS xor key (per column)
    const int n0   = nt * 64;

    const size_t tbaseA = (size_t)half * 8192 + (size_t)(wv * 64 + col) * 16;

    float4 abk[4][4];   // A kstep banks: [s&..][f0p0, f0p1, f1p0, f1p1]
    float4 rb0[2], rb1[2];

    auto issueA = [&](int kt, int s, float4 (&bank)[4]) {
        const char* ga = (const char*)Wst + ((size_t)(mt * NKT + kt) << 17)
                       + ((size_t)s << 15) + tbaseA;
        bank[0] = ld_x4(ga);                 // p0, f0
        bank[1] = ld_x4(ga + 16384);         // p1, f0
        bank[2] = ld_x4(ga + 512);           // p0, f1 (f stride = 32 rows x 16B)
        bank[3] = ld_x4(ga + 16384 + 512);   // p1, f1
    };
    // B: 16KB/chunk staged linearly; XOR swizzle folded into SOURCE decode (rule #21)
    auto issueB = [&](int kt, float4 (&rb)[2]) {
        #pragma unroll
        for (int i = 0; i < 2; ++i) {
            int u = i * 512 + tid;
            int bc = u >> 4, w16 = u & 15;
            int si = w16 ^ (bc & 15);
            int p = si >> 3;
            int kh = kt * 64 + ((si >> 1) & 3) * 16 + (si & 1) * 8;
            const f16* sp = src1; int kl = kh;
            if (NKT == 16 && kh >= 512) { sp = src2; kl = kh - 512; }
            rb[i] = coh_ld_x4(sp + (size_t)(n0 + bc) * 1024 + p * 512 + kl);
        }
    };

    f32x16 accA[2][2] = {};   // [Mfrag f][Nfrag nf]
    f32x16 accB[2][2] = {};

    // prologue — issue order defines the vmcnt queue; do not reorder
    issueB(0, rb0);
    issueB(1, rb1);
    issueA(0, 0, abk[0]);
    issueA(0, 1, abk[1]);

    #pragma unroll
    for (int kt = 0; kt < NKT; ++kt) {
        char* buf = smem + (kt & 1) * 16384;
        wait_vm(kt == NKT - 1 ? 8 : 10);        // B(kt) ready (queue-replay derived)
        if ((kt & 1) == 0) {
            *(float4*)(buf + tid * 16)        = rb0[0];
            *(float4*)(buf + 8192 + tid * 16) = rb0[1];
        } else {
            *(float4*)(buf + tid * 16)        = rb1[0];
            *(float4*)(buf + 8192 + tid * 16) = rb1[1];
        }
        __syncthreads();

        #define KSTEP(S, BK)                                                          \
        {                                                                             \
            f16x8 ah0 = __builtin_bit_cast(f16x8, BK[0]);                             \
            f16x8 al0 = __builtin_bit_cast(f16x8, BK[1]);                             \
            f16x8 ah1 = __builtin_bit_cast(f16x8, BK[2]);                             \
            f16x8 al1 = __builtin_bit_cast(f16x8, BK[3]);                             \
            _Pragma("unroll")                                                         \
            for (int nf = 0; nf < 2; ++nf) {                                          \
                const char* cb = buf + (nf * 32 + col) * 256;                         \
                f16x8 bh = *(const f16x8*)(cb + ((((S) * 2 + half) ^ xk) << 4));      \
                f16x8 bl = *(const f16x8*)(cb + (((8 + (S) * 2 + half) ^ xk) << 4));  \
                accA[0][nf] = __builtin_amdgcn_mfma_f32_32x32x16_f16(ah0, bh, accA[0][nf], 0, 0, 0); \
                accB[0][nf] = __builtin_amdgcn_mfma_f32_32x32x16_f16(al0, bh, accB[0][nf], 0, 0, 0); \
                accB[0][nf] = __builtin_amdgcn_mfma_f32_32x32x16_f16(ah0, bl, accB[0][nf], 0, 0, 0); \
                accA[1][nf] = __builtin_amdgcn_mfma_f32_32x32x16_f16(ah1, bh, accA[1][nf], 0, 0, 0); \
                accB[1][nf] = __builtin_amdgcn_mfma_f32_32x32x16_f16(al1, bh, accB[1][nf], 0, 0, 0); \
                accB[1][nf] = __builtin_amdgcn_mfma_f32_32x32x16_f16(ah1, bl, accB[1][nf], 0, 0, 0); \
            }                                                                         \
        }

        const int w01 = (kt == 0 || kt == NKT - 1) ? 4 : 6;
        wait_vm(w01);                       // A(kt,0)
        KSTEP(0, abk[0])
        issueA(kt, 2, abk[2]);
        wait_vm(w01);                       // A(kt,1)
        KSTEP(1, abk[1])
        issueA(kt, 3, abk[3]);
        wait_vm(4);                         // A(kt,2)
        KSTEP(2, abk[2])
        if (kt + 1 < NKT) issueA(kt + 1, 0, abk[0]);
        wait_vm(kt == NKT - 1 ? 0 : 4);     // A(kt,3)
        KSTEP(3, abk[3])
        if (kt + 1 < NKT) issueA(kt + 1, 1, abk[1]);
        if (kt + 2 < NKT) {                 // B issued LAST -> newest in queue (the fix)
            if ((kt & 1) == 0) issueB(kt + 2, rb0);
            else               issueB(kt + 2, rb1);
        }
        #undef KSTEP
    }

    // ---------------- epilogue: cell update in registers ----------------
    // 32x32 D map: col=lane&31, row=(reg&3)+8*(reg>>2)+4*(lane>>5);
    // rows permuted hl*4+g -> reg=4q+g holds gate g of hl_loc = wv*16+f*8+2q+half.
    const float sA = 1.0f / 1024.0f;
    const float sB = 1.0f / (1024.0f * 2048.0f);
    float4 xq[2];
    if (RANK4) {
        xq[0] = coh_ld_x4(xin + (size_t)(n0 + col) * xstride);
        xq[1] = coh_ld_x4(xin + (size_t)(n0 + 32 + col) * xstride);
        drain_vm();
    }
    uint32_t* htile = (uint32_t*)(smem + 32768);    // disjoint from dbuf
    #pragma unroll
    for (int f = 0; f < 2; ++f) {
        #pragma unroll
        for (int qq = 0; qq < 4; ++qq) {
            const int hl_loc = wv * 16 + f * 8 + 2 * qq + half;
            const int hl = mt * 128 + hl_loc;
            const float4 bv = *(const float4*)(bt4 + hl * 4);
            #pragma unroll
            for (int nf = 0; nf < 2; ++nf) {
                const int col_loc = nf * 32 + col;
                const int n = n0 + col_loc;
                float g0 = accA[f][nf][4 * qq + 0] * sA + accB[f][nf][4 * qq + 0] * sB + bv.x;
                float g1 = accA[f][nf][4 * qq + 1] * sA + accB[f][nf][4 * qq + 1] * sB + bv.y;
                float g2 = accA[f][nf][4 * qq + 2] * sA + accB[f][nf][4 * qq + 2] * sB + bv.z;
                float g3 = accA[f][nf][4 * qq + 3] * sA + accB[f][nf][4 * qq + 3] * sB + bv.w;
                if (RANK4) {
                    const float4* wr = (const float4*)(wih4 + hl * 16);
                    const float4 x4 = xq[nf];
                    g0 += wr[0].x * x4.x + wr[0].y * x4.y + wr[0].z * x4.z + wr[0].w * x4.w;
                    g1 += wr[1].x * x4.x + wr[1].y * x4.y + wr[1].z * x4.z + wr[1].w * x4.w;
                    g2 += wr[2].x * x4.x + wr[2].y * x4.y + wr[2].z * x4.z + wr[2].w * x4.w;
                    g3 += wr[3].x * x4.x + wr[3].y * x4.y + wr[3].z * x4.z + wr[3].w * x4.w;
                }
                const size_t co = (size_t)hl * 1024 + n;   // c: block-private, plain
                const float cold = cT[co];
                const float si = fast_sig(g0);
                const float sf = fast_sig(g1);
                const float so = fast_sig(g3);
                const float cn = sf * cold + si * fast_tanh(g2);
                const float hn = so * fast_tanh(cn);
                cT[co] = cn;
                const float h32v = hn * 32.0f;
                const f16 hi = (f16)h32v;
                const f16 lo = (f16)((h32v - (float)hi) * 2048.0f);
                uint32_t pk = ((uint32_t)__builtin_bit_cast(uint16_t, lo) << 16)
                            | (uint32_t)__builtin_bit_cast(uint16_t, hi);
                htile[col_loc * 129 + hl_loc] = pk;
            }
        }
    }
    __syncthreads();
    // writeout: pack adjacent hl pairs; h row layout = [256 u32 hi][256 u32 lo]
    uint32_t* h32out = (uint32_t*)hout;
    #pragma unroll
    for (int e = 0; e < 16; ++e) {
        int u = e * 512 + tid;              // 0..8191
        int cc = u >> 7;                    // 0..63 batch col
        int rem = u & 127;
        int pl = rem >> 6;                  // 0=hi, 1=lo
        int w = rem & 63;                   // u32 word within 128-hl tile
        uint32_t t0 = htile[cc * 129 + 2 * w];
        uint32_t t1 = htile[cc * 129 + 2 * w + 1];
        uint32_t word = pl ? ((t1 & 0xffff0000u) | (t0 >> 16))
                           : ((t1 << 16) | (t0 & 0xffffu));
        coh_store_u32(h32out + (size_t)(n0 + cc) * 512 + pl * 256 + mt * 64 + w, word);
    }
}

// ---------------- pred + softmax: block covers 16 cols (2 per wave) ----------------
__device__ __forceinline__ void pred_step(
    const f16* __restrict__ h1, const float* __restrict__ Wp, const float* __restrict__ bp,
    float* __restrict__ outp, float* __restrict__ xfb, int t, int mt, int nt)
{
    const int lane = threadIdx.x & 63;
    const int wv = threadIdx.x >> 6;        // 0..7
    #pragma unroll
    for (int it = 0; it < 2; ++it) {
        const int n = nt * 64 + mt * 16 + it * 8 + wv;
        const f16* hr = h1 + (size_t)n * 1024;
        const int k0 = lane * 8;
        float4 hv4 = coh_ld_x4(hr + k0);
        float4 lv4 = coh_ld_x4(hr + 512 + k0);
        drain_vm();
        f16x8 hv = __builtin_bit_cast(f16x8, hv4);
        f16x8 lv = __builtin_bit_cast(f16x8, lv4);
        float h[8];
        #pragma unroll
        for (int e = 0; e < 8; ++e)
            h[e] = (float)hv[e] * 0.03125f + (float)lv[e] * (1.0f / 65536.0f);
        float a[4] = {};
        #pragma unroll
        for (int g = 0; g < 4; ++g) {
            const float4 wa = *(const float4*)(Wp + g * HD + k0);
            const float4 wb = *(const float4*)(Wp + g * HD + k0 + 4);
            a[g] = h[0]*wa.x + h[1]*wa.y + h[2]*wa.z + h[3]*wa.w
                 + h[4]*wb.x + h[5]*wb.y + h[6]*wb.z + h[7]*wb.w;
        }
        #pragma unroll
        for (int off = 32; off > 0; off >>= 1) {
            a[0] += __shfl_xor(a[0], off);
            a[1] += __shfl_xor(a[1], off);
            a[2] += __shfl_xor(a[2], off);
            a[3] += __shfl_xor(a[3], off);
        }
        if (lane == 0) {
            const float4 bv = *(const float4*)bp;
            float v0 = a[0] + bv.x, v1 = a[1] + bv.y, v2 = a[2] + bv.z, v3 = a[3] + bv.w;
            float* op = outp + (size_t)n * (TST * 4) + t * 4;
            op[0] = v0; op[1] = v1; op[2] = v2; op[3] = v3;
            float m = fmaxf(fmaxf(v0, v1), fmaxf(v2, v3));
            float e0 = expf(v0 - m), e1 = expf(v1 - m), e2 = expf(v2 - m), e3 = expf(v3 - m);
            float inv = 1.0f / (e0 + e1 + e2 + e3);
            uint32_t* xp = (uint32_t*)(xfb + n * 4);
            float s0 = e0 * inv, s1 = e1 * inv, s2 = e2 * inv, s3 = e3 * inv;
            coh_store_u32(xp + 0, __builtin_bit_cast(uint32_t, s0));
            coh_store_u32(xp + 1, __builtin_bit_cast(uint32_t, s1));
            coh_store_u32(xp + 2, __builtin_bit_cast(uint32_t, s2));
            coh_store_u32(xp + 3, __builtin_bit_cast(uint32_t, s3));
        }
    }
}

// ---------------- persistent whole-network kernel ----------------
struct Params {
    const f16 *WE0, *WE1, *WD0, *WD1;
    const float *wih4E, *wih4D, *btE0, *btE1, *btD0, *btD1;
    const float *X, *Wp, *bp;
    f16 *h0a, *h0b, *h1a, *h1b;
    float *c0, *c1;
    float *xfb0, *xfb1;
    float *out;
    int *f0, *f1, *fp;   // [16 groups][4 blocks x 16 ints]
};

__launch_bounds__(512, 1) __global__ void lstm_persistent(Params P)
{
    __shared__ __align__(16) char smem[32768 + 33024];   // 2x16KB B dbuf + htile[64][129]
    const int bx = blockIdx.x;
    const int mt = bx & 3;       // constant per XCD (round-robin) -> 3MB W slice L2-resident
    const int nt = bx >> 2;      // 0..15 batch-column group (64 cols)
    int* f0g = P.f0 + nt * 64;
    int* f1g = P.f1 + nt * 64;
    int* fpg = P.fp + nt * 64;
    int* my0 = f0g + mt * 16;
    int* my1 = f1g + mt * 16;
    int* myp = fpg + mt * 16;
    f16* h0b_[2] = { P.h0a, P.h0b };
    f16* h1b_[2] = { P.h1a, P.h1b };
    float* xfb_[2] = { P.xfb0, P.xfb1 };

    for (int u = 0; u < 2 * TST; ++u) {
        const bool enc = (u < TST);
        const int t = enc ? u : u - TST;

        // ---- layer 0 ---- (f0 >= u: group's l0(u-1) done; WAR-safe by program order)
        if (enc) wait2(f0g, u, f0g, u);
        else     wait2(f0g, u, fpg, t);    // + xfb(t-1) ready
        layer_step<8, true>(enc ? P.WE0 : P.WD0,
                            h0b_[(u + 1) & 1], nullptr,
                            enc ? P.wih4E : P.wih4D,
                            enc ? (P.X + t * 4) : xfb_[(t + 1) & 1],
                            enc ? (TST * 4) : 4,
                            enc ? P.btE0 : P.btD0,
                            P.c0, h0b_[u & 1], smem, mt, nt);
        publish(my0, u + 1);

        // ---- layer 1 ---- (h0(u) ready AND h1(u-1) ready)
        wait2(f0g, u + 1, f1g, u);
        layer_step<16, false>(enc ? P.WE1 : P.WD1,
                              h0b_[u & 1], h1b_[(u + 1) & 1],
                              nullptr, nullptr, 0,
                              enc ? P.btE1 : P.btD1,
                              P.c1, h1b_[u & 1], smem, mt, nt);
        publish(my1, u + 1);

        // ---- pred + softmax feedback (decoder only) ----
        if (!enc) {
            wait2(f1g, u + 1, f1g, u + 1);   // full h1(t) rows from group
            pred_step(h1b_[u & 1], P.Wp, P.bp, P.out, xfb_[t & 1], t, mt, nt);
            publish(myp, t + 1);
        }
    }
}

// ---------------- host ----------------
extern "C" void kernel_launch(void* const* d_in, const int* in_sizes, int n_in,
                              void* d_out, int out_size, void* d_ws, size_t ws_size,
                              hipStream_t stream)
{
    const float* X     = (const float*)d_in[0];
    const float* eWih0 = (const float*)d_in[2];
    const float* eWhh0 = (const float*)d_in[3];
    const float* eb0   = (const float*)d_in[4];
    const float* eWih1 = (const float*)d_in[5];
    const float* eWhh1 = (const float*)d_in[6];
    const float* eb1   = (const float*)d_in[7];
    const float* dWih0 = (const float*)d_in[8];
    const float* dWhh0 = (const float*)d_in[9];
    const float* db0   = (const float*)d_in[10];
    const float* dWih1 = (const float*)d_in[11];
    const float* dWhh1 = (const float*)d_in[12];
    const float* db1   = (const float*)d_in[13];
    const float* Wp    = (const float*)d_in[14];
    const float* bp    = (const float*)d_in[15];

    char* ws = (char*)d_ws;
    size_t off = 0;
    auto alloc = [&](size_t bytes) { char* p = ws + off; off += (bytes + 255) & ~(size_t)255; return p; };
    f16* WE0 = (f16*)alloc((size_t)4 * 8  * 131072);
    f16* WE1 = (f16*)alloc((size_t)4 * 16 * 131072);
    f16* WD0 = (f16*)alloc((size_t)4 * 8  * 131072);
    f16* WD1 = (f16*)alloc((size_t)4 * 16 * 131072);
    float* wih4E = (float*)alloc(8192 * 4);
    float* wih4D = (float*)alloc(8192 * 4);
    float* btE0 = (float*)alloc(2048 * 4);
    float* btE1 = (float*)alloc(2048 * 4);
    float* btD0 = (float*)alloc(2048 * 4);
    float* btD1 = (float*)alloc(2048 * 4);
    f16* h0a = (f16*)alloc((size_t)BATCH * 1024 * 2);
    f16* h0b = (f16*)alloc((size_t)BATCH * 1024 * 2);
    f16* h1a = (f16*)alloc((size_t)BATCH * 1024 * 2);
    f16* h1b = (f16*)alloc((size_t)BATCH * 1024 * 2);
    float* c0  = (float*)alloc((size_t)HD * BATCH * 4);
    float* c1  = (float*)alloc((size_t)HD * BATCH * 4);
    float* xfb0 = (float*)alloc((size_t)BATCH * 4 * 4);
    float* xfb1 = (float*)alloc((size_t)BATCH * 4 * 4);
    int* f0 = (int*)alloc(16 * 64 * 4);
    int* f1 = (int*)alloc(16 * 64 * 4);
    int* fp = (int*)alloc(16 * 64 * 4);
    if (off > ws_size) return;   // workspace too small -> loud failure

    // one-time (per-call) weight prep
    split_w<<<(4 * 8  * 8192) / 256, 256, 0, stream>>>(nullptr, 0,   eWhh0, 8,  WE0);
    split_w<<<(4 * 16 * 8192) / 256, 256, 0, stream>>>(eWih1, 512, eWhh1, 16, WE1);
    split_w<<<(4 * 8  * 8192) / 256, 256, 0, stream>>>(nullptr, 0,   dWhh0, 8,  WD0);
    split_w<<<(4 * 16 * 8192) / 256, 256, 0, stream>>>(dWih1, 512, dWhh1, 16, WD1);
    prep_wih4<<<32, 256, 0, stream>>>(eWih0, wih4E);
    prep_wih4<<<32, 256, 0, stream>>>(dWih0, wih4D);
    prep_b4<<<8, 256, 0, stream>>>(eb0, btE0);
    prep_b4<<<8, 256, 0, stream>>>(eb1, btE1);
    prep_b4<<<8, 256, 0, stream>>>(db0, btD0);
    prep_b4<<<8, 256, 0, stream>>>(db1, btD1);

    hipMemsetAsync(h0b, 0, (size_t)BATCH * 1024 * 2, stream);   // h0 parity-1 (read at u=0)
    hipMemsetAsync(h1b, 0, (size_t)BATCH * 1024 * 2, stream);   // h1 parity-1
    hipMemsetAsync(c0, 0, (size_t)HD * BATCH * 4, stream);
    hipMemsetAsync(c1, 0, (size_t)HD * BATCH * 4, stream);
    hipMemsetAsync(xfb1, 0, (size_t)BATCH * 4 * 4, stream);     // x feedback at dec t=0
    hipMemsetAsync(f0, 0, 16 * 64 * 4, stream);
    hipMemsetAsync(f1, 0, 16 * 64 * 4, stream);
    hipMemsetAsync(fp, 0, 16 * 64 * 4, stream);

    Params P;
    P.WE0 = WE0; P.WE1 = WE1; P.WD0 = WD0; P.WD1 = WD1;
    P.wih4E = wih4E; P.wih4D = wih4D;
    P.btE0 = btE0; P.btE1 = btE1; P.btD0 = btD0; P.btD1 = btD1;
    P.X = X; P.Wp = Wp; P.bp = bp;
    P.h0a = h0a; P.h0b = h0b; P.h1a = h1a; P.h1b = h1b;
    P.c0 = c0; P.c1 = c1;
    P.xfb0 = xfb0; P.xfb1 = xfb1;
    P.out = (float*)d_out;
    P.f0 = f0; P.f1 = f1; P.fp = fp;

    lstm_persistent<<<64, 512, 0, stream>>>(P);

    (void)in_sizes; (void)n_in; (void)out_size;
}

// Round 11
// 7764.896 us; speedup vs baseline: 2.3063x; 2.3063x over previous
//
#include <hip/hip_runtime.h>
#include <math.h>
#include <stdint.h>

typedef _Float16 f16;
typedef _Float16 f16x8 __attribute__((ext_vector_type(8)));
typedef float f32x4 __attribute__((ext_vector_type(4)));

#define BATCH 1024
#define HD    512
#define TST   100
#define BUFSZ 20480   // 16KB A + 4KB B per BK=32 chunk

// ---------------- access primitives ----------------
__device__ __forceinline__ float4 coh_ld_x4(const void* p) {
    float4 v;
    asm volatile("global_load_dwordx4 %0, %1, off sc0 sc1" : "=v"(v) : "v"(p) : "memory");
    return v;
}
__device__ __forceinline__ float4 ld_x4(const void* p) {
    float4 v;
    asm volatile("global_load_dwordx4 %0, %1, off" : "=v"(v) : "v"(p) : "memory");
    return v;
}
__device__ __forceinline__ void coh_store_u32(uint32_t* p, uint32_t v) {
    asm volatile("global_store_dword %0, %1, off sc0 sc1" :: "v"(p), "v"(v) : "memory");
}
__device__ __forceinline__ void coh_store_i32(int* p, int v) {
    asm volatile("global_store_dword %0, %1, off sc0 sc1" :: "v"(p), "v"(v) : "memory");
}
__device__ __forceinline__ int coh_load_i32(const int* p) {
    int v;
    asm volatile("global_load_dword %0, %1, off sc0 sc1\n\ts_waitcnt vmcnt(0)"
                 : "=v"(v) : "v"(p) : "memory");
    return v;
}
__device__ __forceinline__ void drain_vm() {
    asm volatile("s_waitcnt vmcnt(0)" ::: "memory");
    __builtin_amdgcn_sched_barrier(0);
}
__device__ __forceinline__ void wait_vm(int n) {   // folds after unroll
    if (n == 0) asm volatile("s_waitcnt vmcnt(0)" ::: "memory");
    else        asm volatile("s_waitcnt vmcnt(5)" ::: "memory");
    __builtin_amdgcn_sched_barrier(0);
}

// fast transcendentals (validated: R8/R9 absmax 1.5e-5 vs 1e-4 threshold)
__device__ __forceinline__ float fast_sig(float x) {
    return 1.0f / (1.0f + __expf(-x));
}
__device__ __forceinline__ float fast_tanh(float x) {
    float xc = fminf(fmaxf(x, -15.0f), 15.0f);
    float e = __expf(2.0f * xc);
    return 1.0f - 2.0f / (e + 1.0f);
}

// ---------------- setup kernels ----------------
// LDS image per (mt 0..15, kt): 128 lines x 8 slots x 16B = 16KB.
// content slot s = pos ^ (line&7); s = plane*4 + k-octet.
__global__ void split_w(const float* __restrict__ src0, int ksplit,
                        const float* __restrict__ src1, int NKT, f16* __restrict__ out)
{
    int c = blockIdx.x * 256 + threadIdx.x;
    int total = 16 * NKT * 1024;
    if (c >= total) return;
    int u = c & 1023;
    int t2 = c >> 10;            // mt*NKT + kt
    int kt = t2 % NKT;
    int mt = t2 / NKT;
    int line = u >> 3, pos = u & 7;
    int s = pos ^ (line & 7);
    int plane = s >> 2, o = s & 3;
    int m = mt * 128 + line;
    int orow = (m & 3) * HD + (m >> 2);     // original row g*512+hl (rows permuted hl*4+g)
    int kb = kt * 32 + o * 8;
    f16 v[8];
    #pragma unroll
    for (int e = 0; e < 8; ++e) {
        int k = kb + e;
        float w = (k < ksplit) ? src0[(size_t)orow * ksplit + k]
                               : src1[(size_t)orow * HD + (k - ksplit)];
        float w32 = w * 32.0f;
        f16 hi = (f16)w32;
        v[e] = plane ? (f16)((w32 - (float)hi) * 2048.0f) : hi;
    }
    *(f16x8*)(out + (size_t)c * 8) = *(f16x8*)v;
}

__global__ void prep_b4(const float* __restrict__ b, float* __restrict__ bt) {
    int c = blockIdx.x * 256 + threadIdx.x;     // c = hl*4+g
    if (c < 2048) bt[c] = b[(c & 3) * HD + (c >> 2)];
}

__global__ void prep_wih4(const float* __restrict__ W, float* __restrict__ o) {
    int c = blockIdx.x * 256 + threadIdx.x;     // c = hl*16 + g*4 + j
    if (c < 8192) {
        int j = c & 3, g = (c >> 2) & 3, hl = c >> 4;
        o[c] = W[(size_t)(g * HD + hl) * 4 + j];
    }
}

// ---------------- cross-block sync: per-block epoch cells (proven R7-R9) ----------------
__device__ __forceinline__ void publish(int* cell, int epoch) {
    drain_vm();
    __syncthreads();
    if (threadIdx.x == 0)
        coh_store_i32(cell, epoch);
}
__device__ __forceinline__ void wait2(const int* a, int ta, const int* b, int tb) {
    if (threadIdx.x < 64) {
        const int l = threadIdx.x & 15;
        const bool useB = (threadIdx.x & 16) != 0;
        const int* p = (useB ? b : a) + l * 16;
        const int tgt = useB ? tb : ta;
        for (;;) {
            int v = coh_load_i32(p);
            if (__all(v >= tgt)) break;
            __builtin_amdgcn_s_sleep(2);
        }
    }
    __syncthreads();
}

// ---------------- fused LSTM layer-step: BM=128 x BN=32, BK=32, 4 waves ----------------
template<int NKT, bool RANK4>
__device__ __forceinline__ void layer_step(
    const f16* __restrict__ Wst, const f16* __restrict__ src1, const f16* __restrict__ src2,
    const float* __restrict__ wih4, const float* __restrict__ xin, int xstride,
    const float* __restrict__ bt4, float* __restrict__ cT, f16* __restrict__ hout,
    char* smem, int mt, int nt)
{
    const int tid  = threadIdx.x;
    const int lane = tid & 63;
    const int wv   = tid >> 6;          // wave 0..3
    const int wm   = wv & 1, wn = wv >> 1;
    const int l15  = lane & 15, j = lane >> 4;
    const int n0   = nt * 32;
    const int key  = (j ^ (l15 & 7)) << 4;   // slot-XOR swizzle key

    int ALr[4];
    #pragma unroll
    for (int f = 0; f < 4; ++f) ALr[f] = (wm * 64 + f * 16 + l15) * 128;
    const int BLb = 16384 + (wn * 16 + l15) * 128;

    float4 ra0[4], ra1[4];   // A banks (depth 2): 4 ld_x4/thread/chunk
    float4 rb0, rb1;         // B banks (depth 2): 1 ld_x4/thread/chunk
    float4 xv = make_float4(0.f, 0.f, 0.f, 0.f);

    auto issueA = [&](int kt, float4 (&ra)[4]) {
        const f16* ga = Wst + ((size_t)(mt * NKT + kt)) * 8192;
        #pragma unroll
        for (int i = 0; i < 4; ++i)
            ra[i] = ld_x4(ga + (size_t)(i * 256 + tid) * 8);
    };
    auto issueB = [&](int kt, float4& rb) {
        int bc = tid >> 3, pos = tid & 7;
        int si = pos ^ (bc & 7);
        int plane = si >> 2;
        int kh = kt * 32 + (si & 3) * 8;
        const f16* sp = src1; int kl = kh;
        if (NKT == 32 && kh >= 512) { sp = src2; kl = kh - 512; }
        rb = coh_ld_x4(sp + (size_t)(n0 + bc) * 1024 + plane * 512 + kl);
    };

    f32x4 accA[4] = {};
    f32x4 accB[4] = {};

    // prologue — issue order defines the vmcnt queue; do not reorder
    if (RANK4) xv = coh_ld_x4(xin + (size_t)(n0 + wn * 16 + l15) * xstride);
    issueB(0, rb0); issueA(0, ra0); issueB(1, rb1); issueA(1, ra1);

    #pragma unroll
    for (int kt = 0; kt < NKT; ++kt) {
        char* buf = smem + (kt & 1) * BUFSZ;
        wait_vm(kt == NKT - 1 ? 0 : 5);      // A(kt)+B(kt) done; keep next chunk in flight
        const float4* rap = (kt & 1) ? ra1 : ra0;
        #pragma unroll
        for (int i = 0; i < 4; ++i)
            *(float4*)(buf + (i * 256 + tid) * 16) = rap[i];
        *(float4*)(buf + 16384 + tid * 16) = (kt & 1) ? rb1 : rb0;
        if (kt + 2 < NKT) {                  // refill just-consumed banks
            if ((kt & 1) == 0) { issueB(kt + 2, rb0); issueA(kt + 2, ra0); }
            else               { issueB(kt + 2, rb1); issueA(kt + 2, ra1); }
        }
        __syncthreads();
        f16x8 bh = *(const f16x8*)(buf + BLb + key);
        f16x8 bl = *(const f16x8*)(buf + BLb + (key ^ 0x40));
        #pragma unroll
        for (int f = 0; f < 4; ++f) {
            f16x8 ah = *(const f16x8*)(buf + ALr[f] + key);
            f16x8 al = *(const f16x8*)(buf + ALr[f] + (key ^ 0x40));
            accA[f] = __builtin_amdgcn_mfma_f32_16x16x32_f16(ah, bh, accA[f], 0, 0, 0);
            accB[f] = __builtin_amdgcn_mfma_f32_16x16x32_f16(al, bh, accB[f], 0, 0, 0);
            accB[f] = __builtin_amdgcn_mfma_f32_16x16x32_f16(ah, bl, accB[f], 0, 0, 0);
        }
    }

    // ---------------- epilogue: cell update in registers ----------------
    // 16x16 D map: col=lane&15, row=(lane>>4)*4+r; rows permuted hl*4+g ->
    // regs r=0..3 are gates i,f,g,o of hl_loc = wm*16 + f*4 + j.
    const float sA = 1.0f / 1024.0f;
    const float sB = 1.0f / (1024.0f * 2048.0f);
    uint32_t* htile = (uint32_t*)(smem + 2 * BUFSZ);   // disjoint from dbuf
    #pragma unroll
    for (int f = 0; f < 4; ++f) {
        const int hl_loc = wm * 16 + f * 4 + j;
        const int hl = mt * 32 + hl_loc;
        const float4 bv = *(const float4*)(bt4 + hl * 4);
        const int n_loc = wn * 16 + l15;
        const int n = n0 + n_loc;
        float g0 = accA[f][0] * sA + accB[f][0] * sB + bv.x;
        float g1 = accA[f][1] * sA + accB[f][1] * sB + bv.y;
        float g2 = accA[f][2] * sA + accB[f][2] * sB + bv.z;
        float g3 = accA[f][3] * sA + accB[f][3] * sB + bv.w;
        if (RANK4) {
            const float4* wr = (const float4*)(wih4 + hl * 16);
            g0 += wr[0].x * xv.x + wr[0].y * xv.y + wr[0].z * xv.z + wr[0].w * xv.w;
            g1 += wr[1].x * xv.x + wr[1].y * xv.y + wr[1].z * xv.z + wr[1].w * xv.w;
            g2 += wr[2].x * xv.x + wr[2].y * xv.y + wr[2].z * xv.z + wr[2].w * xv.w;
            g3 += wr[3].x * xv.x + wr[3].y * xv.y + wr[3].z * xv.z + wr[3].w * xv.w;
        }
        const size_t co = (size_t)hl * 1024 + n;   // c: block-private, plain cached
        const float cold = cT[co];
        const float si = fast_sig(g0);
        const float sf = fast_sig(g1);
        const float so = fast_sig(g3);
        const float cn = sf * cold + si * fast_tanh(g2);
        const float hn = so * fast_tanh(cn);
        cT[co] = cn;
        const float h32v = hn * 32.0f;
        const f16 hi = (f16)h32v;
        const f16 lo = (f16)((h32v - (float)hi) * 2048.0f);
        uint32_t pk = ((uint32_t)__builtin_bit_cast(uint16_t, lo) << 16)
                    | (uint32_t)__builtin_bit_cast(uint16_t, hi);
        htile[n_loc * 33 + hl_loc] = pk;
    }
    __syncthreads();
    // writeout: pack adjacent hl pairs; h row layout = [256 u32 hi][256 u32 lo]
    uint32_t* h32out = (uint32_t*)hout;
    #pragma unroll
    for (int i = 0; i < 4; ++i) {
        int u = i * 256 + tid;              // 0..1023
        int cc = u >> 5;                    // 0..31 batch col
        int rem = u & 31;
        int pl = rem >> 4;                  // 0=hi, 1=lo
        int w = rem & 15;                   // u32 word within 32-hl tile
        uint32_t t0 = htile[cc * 33 + 2 * w];
        uint32_t t1 = htile[cc * 33 + 2 * w + 1];
        uint32_t word = pl ? ((t1 & 0xffff0000u) | (t0 >> 16))
                           : ((t1 << 16) | (t0 & 0xffffu));
        coh_store_u32(h32out + (size_t)(n0 + cc) * 512 + pl * 256 + mt * 16 + w, word);
    }
}

// ---------------- pred + softmax: 2 rows per block (waves 0,1) ----------------
__device__ __forceinline__ void pred_step(
    const f16* __restrict__ h1, const float* __restrict__ Wp, const float* __restrict__ bp,
    float* __restrict__ outp, float* __restrict__ xfb, int t, int mt, int nt)
{
    const int lane = threadIdx.x & 63;
    const int wv = threadIdx.x >> 6;
    if (wv >= 2) return;
    const int n = nt * 32 + mt * 2 + wv;
    const f16* hr = h1 + (size_t)n * 1024;
    const int k0 = lane * 8;
    float4 hv4 = coh_ld_x4(hr + k0);
    float4 lv4 = coh_ld_x4(hr + 512 + k0);
    drain_vm();
    f16x8 hv = __builtin_bit_cast(f16x8, hv4);
    f16x8 lv = __builtin_bit_cast(f16x8, lv4);
    float h[8];
    #pragma unroll
    for (int e = 0; e < 8; ++e)
        h[e] = (float)hv[e] * 0.03125f + (float)lv[e] * (1.0f / 65536.0f);
    float a[4] = {};
    #pragma unroll
    for (int g = 0; g < 4; ++g) {
        const float4 wa = *(const float4*)(Wp + g * HD + k0);
        const float4 wb = *(const float4*)(Wp + g * HD + k0 + 4);
        a[g] = h[0]*wa.x + h[1]*wa.y + h[2]*wa.z + h[3]*wa.w
             + h[4]*wb.x + h[5]*wb.y + h[6]*wb.z + h[7]*wb.w;
    }
    #pragma unroll
    for (int off = 32; off > 0; off >>= 1) {
        a[0] += __shfl_xor(a[0], off);
        a[1] += __shfl_xor(a[1], off);
        a[2] += __shfl_xor(a[2], off);
        a[3] += __shfl_xor(a[3], off);
    }
    if (lane == 0) {
        const float4 bv = *(const float4*)bp;
        float v0 = a[0] + bv.x, v1 = a[1] + bv.y, v2 = a[2] + bv.z, v3 = a[3] + bv.w;
        float* op = outp + (size_t)n * (TST * 4) + t * 4;
        op[0] = v0; op[1] = v1; op[2] = v2; op[3] = v3;
        float m = fmaxf(fmaxf(v0, v1), fmaxf(v2, v3));
        float e0 = expf(v0 - m), e1 = expf(v1 - m), e2 = expf(v2 - m), e3 = expf(v3 - m);
        float inv = 1.0f / (e0 + e1 + e2 + e3);
        uint32_t* xp = (uint32_t*)(xfb + n * 4);
        float s0 = e0 * inv, s1 = e1 * inv, s2 = e2 * inv, s3 = e3 * inv;
        coh_store_u32(xp + 0, __builtin_bit_cast(uint32_t, s0));
        coh_store_u32(xp + 1, __builtin_bit_cast(uint32_t, s1));
        coh_store_u32(xp + 2, __builtin_bit_cast(uint32_t, s2));
        coh_store_u32(xp + 3, __builtin_bit_cast(uint32_t, s3));
    }
}

// ---------------- persistent whole-network kernel ----------------
struct Params {
    const f16 *WE0, *WE1, *WD0, *WD1;
    const float *wih4E, *wih4D, *btE0, *btE1, *btD0, *btD1;
    const float *X, *Wp, *bp;
    f16 *h0a, *h0b, *h1a, *h1b;
    float *c0, *c1;
    float *xfb0, *xfb1;
    float *out;
    int *f0, *f1, *fp;   // [32 groups][16 blocks x 16 ints]
};

__launch_bounds__(256, 2) __global__ void lstm_persistent(Params P)
{
    __shared__ __align__(16) char smem[2 * BUFSZ + 4224];   // 40KB dbuf + htile[32][33]
    const int bx = blockIdx.x;
    const int mt = ((bx & 7) << 1) | ((bx >> 3) & 1);  // 0..15 (2 W-slices/XCD, L2-resident)
    const int nt = bx >> 4;                            // 0..31 batch-column group (32 cols)
    int* f0g = P.f0 + nt * 256;
    int* f1g = P.f1 + nt * 256;
    int* fpg = P.fp + nt * 256;
    int* my0 = f0g + mt * 16;
    int* my1 = f1g + mt * 16;
    int* myp = fpg + mt * 16;
    f16* h0b_[2] = { P.h0a, P.h0b };
    f16* h1b_[2] = { P.h1a, P.h1b };
    float* xfb_[2] = { P.xfb0, P.xfb1 };

    for (int u = 0; u < 2 * TST; ++u) {
        const bool enc = (u < TST);
        const int t = enc ? u : u - TST;

        // ---- layer 0 ---- (f0 >= u: group's l0(u-1) done; WAR-safe by program order)
        if (enc) wait2(f0g, u, f0g, u);
        else     wait2(f0g, u, fpg, t);    // + xfb(t-1) ready
        layer_step<16, true>(enc ? P.WE0 : P.WD0,
                             h0b_[(u + 1) & 1], nullptr,
                             enc ? P.wih4E : P.wih4D,
                             enc ? (P.X + t * 4) : xfb_[(t + 1) & 1],
                             enc ? (TST * 4) : 4,
                             enc ? P.btE0 : P.btD0,
                             P.c0, h0b_[u & 1], smem, mt, nt);
        publish(my0, u + 1);

        // ---- layer 1 ---- (h0(u) ready AND h1(u-1) ready)
        wait2(f0g, u + 1, f1g, u);
        layer_step<32, false>(enc ? P.WE1 : P.WD1,
                              h0b_[u & 1], h1b_[(u + 1) & 1],
                              nullptr, nullptr, 0,
                              enc ? P.btE1 : P.btD1,
                              P.c1, h1b_[u & 1], smem, mt, nt);
        publish(my1, u + 1);

        // ---- pred + softmax feedback (decoder only) ----
        if (!enc) {
            wait2(f1g, u + 1, f1g, u + 1);   // full h1(t) rows from group
            pred_step(h1b_[u & 1], P.Wp, P.bp, P.out, xfb_[t & 1], t, mt, nt);
            publish(myp, t + 1);
        }
    }
}

// ---------------- host ----------------
extern "C" void kernel_launch(void* const* d_in, const int* in_sizes, int n_in,
                              void* d_out, int out_size, void* d_ws, size_t ws_size,
                              hipStream_t stream)
{
    const float* X     = (const float*)d_in[0];
    const float* eWih0 = (const float*)d_in[2];
    const float* eWhh0 = (const float*)d_in[3];
    const float* eb0   = (const float*)d_in[4];
    const float* eWih1 = (const float*)d_in[5];
    const float* eWhh1 = (const float*)d_in[6];
    const float* eb1   = (const float*)d_in[7];
    const float* dWih0 = (const float*)d_in[8];
    const float* dWhh0 = (const float*)d_in[9];
    const float* db0   = (const float*)d_in[10];
    const float* dWih1 = (const float*)d_in[11];
    const float* dWhh1 = (const float*)d_in[12];
    const float* db1   = (const float*)d_in[13];
    const float* Wp    = (const float*)d_in[14];
    const float* bp    = (const float*)d_in[15];

    char* ws = (char*)d_ws;
    size_t off = 0;
    auto alloc = [&](size_t bytes) { char* p = ws + off; off += (bytes + 255) & ~(size_t)255; return p; };
    f16* WE0 = (f16*)alloc((size_t)16 * 16 * 16384);
    f16* WE1 = (f16*)alloc((size_t)16 * 32 * 16384);
    f16* WD0 = (f16*)alloc((size_t)16 * 16 * 16384);
    f16* WD1 = (f16*)alloc((size_t)16 * 32 * 16384);
    float* wih4E = (float*)alloc(8192 * 4);
    float* wih4D = (float*)alloc(8192 * 4);
    float* btE0 = (float*)alloc(2048 * 4);
    float* btE1 = (float*)alloc(2048 * 4);
    float* btD0 = (float*)alloc(2048 * 4);
    float* btD1 = (float*)alloc(2048 * 4);
    f16* h0a = (f16*)alloc((size_t)BATCH * 1024 * 2);
    f16* h0b = (f16*)alloc((size_t)BATCH * 1024 * 2);
    f16* h1a = (f16*)alloc((size_t)BATCH * 1024 * 2);
    f16* h1b = (f16*)alloc((size_t)BATCH * 1024 * 2);
    float* c0  = (float*)alloc((size_t)HD * BATCH * 4);
    float* c1  = (float*)alloc((size_t)HD * BATCH * 4);
    float* xfb0 = (float*)alloc((size_t)BATCH * 4 * 4);
    float* xfb1 = (float*)alloc((size_t)BATCH * 4 * 4);
    int* f0 = (int*)alloc(32 * 256 * 4);
    int* f1 = (int*)alloc(32 * 256 * 4);
    int* fp = (int*)alloc(32 * 256 * 4);
    if (off > ws_size) return;   // workspace too small -> loud failure

    // one-time (per-call) weight prep
    split_w<<<(16 * 16 * 1024) / 256, 256, 0, stream>>>(nullptr, 0,   eWhh0, 16, WE0);
    split_w<<<(16 * 32 * 1024) / 256, 256, 0, stream>>>(eWih1, 512, eWhh1, 32, WE1);
    split_w<<<(16 * 16 * 1024) / 256, 256, 0, stream>>>(nullptr, 0,   dWhh0, 16, WD0);
    split_w<<<(16 * 32 * 1024) / 256, 256, 0, stream>>>(dWih1, 512, dWhh1, 32, WD1);
    prep_wih4<<<32, 256, 0, stream>>>(eWih0, wih4E);
    prep_wih4<<<32, 256, 0, stream>>>(dWih0, wih4D);
    prep_b4<<<8, 256, 0, stream>>>(eb0, btE0);
    prep_b4<<<8, 256, 0, stream>>>(eb1, btE1);
    prep_b4<<<8, 256, 0, stream>>>(db0, btD0);
    prep_b4<<<8, 256, 0, stream>>>(db1, btD1);

    hipMemsetAsync(h0b, 0, (size_t)BATCH * 1024 * 2, stream);   // h0 parity-1 (read at u=0)
    hipMemsetAsync(h1b, 0, (size_t)BATCH * 1024 * 2, stream);   // h1 parity-1
    hipMemsetAsync(c0, 0, (size_t)HD * BATCH * 4, stream);
    hipMemsetAsync(c1, 0, (size_t)HD * BATCH * 4, stream);
    hipMemsetAsync(xfb1, 0, (size_t)BATCH * 4 * 4, stream);     // x feedback at dec t=0
    hipMemsetAsync(f0, 0, 32 * 256 * 4, stream);
    hipMemsetAsync(f1, 0, 32 * 256 * 4, stream);
    hipMemsetAsync(fp, 0, 32 * 256 * 4, stream);

    Params P;
    P.WE0 = WE0; P.WE1 = WE1; P.WD0 = WD0; P.WD1 = WD1;
    P.wih4E = wih4E; P.wih4D = wih4D;
    P.btE0 = btE0; P.btE1 = btE1; P.btD0 = btD0; P.btD1 = btD1;
    P.X = X; P.Wp = Wp; P.bp = bp;
    P.h0a = h0a; P.h0b = h0b; P.h1a = h1a; P.h1b = h1b;
    P.c0 = c0; P.c1 = c1;
    P.xfb0 = xfb0; P.xfb1 = xfb1;
    P.out = (float*)d_out;
    P.f0 = f0; P.f1 = f1; P.fp = fp;

    lstm_persistent<<<512, 256, 0, stream>>>(P);

    (void)in_sizes; (void)n_in; (void)out_size;
}

// Round 14
// 7382.914 us; speedup vs baseline: 2.4256x; 1.0517x over previous
//
#include <hip/hip_runtime.h>
#include <math.h>
#include <stdint.h>

typedef _Float16 f16;
typedef _Float16 f16x8 __attribute__((ext_vector_type(8)));
typedef float f32x4 __attribute__((ext_vector_type(4)));

#define BATCH 1024
#define HD    512
#define TST   100
#define BUFSZ 49152   // 32KB A-tile + 16KB B-tile per kt-chunk

// ---------------- access primitives ----------------
__device__ __forceinline__ float4 coh_ld_x4(const void* p) {
    float4 v;
    asm volatile("global_load_dwordx4 %0, %1, off sc0 sc1" : "=v"(v) : "v"(p) : "memory");
    return v;
}
__device__ __forceinline__ float4 ld_x4(const void* p) {
    float4 v;
    asm volatile("global_load_dwordx4 %0, %1, off" : "=v"(v) : "v"(p) : "memory");
    return v;
}
__device__ __forceinline__ void coh_store_u32(uint32_t* p, uint32_t v) {
    asm volatile("global_store_dword %0, %1, off sc0 sc1" :: "v"(p), "v"(v) : "memory");
}
__device__ __forceinline__ void coh_store_i32(int* p, int v) {
    asm volatile("global_store_dword %0, %1, off sc0 sc1" :: "v"(p), "v"(v) : "memory");
}
__device__ __forceinline__ int coh_load_i32(const int* p) {
    int v;
    asm volatile("global_load_dword %0, %1, off sc0 sc1\n\ts_waitcnt vmcnt(0)"
                 : "=v"(v) : "v"(p) : "memory");
    return v;
}
__device__ __forceinline__ void drain_vm() {
    asm volatile("s_waitcnt vmcnt(0)" ::: "memory");
    __builtin_amdgcn_sched_barrier(0);
}
// counted wait; n is compile-time constant after full unroll -> switch folds
__device__ __forceinline__ void wait_vm(int n) {
    switch (n) {
    case 0:  asm volatile("s_waitcnt vmcnt(0)"  ::: "memory"); break;
    case 4:  asm volatile("s_waitcnt vmcnt(4)"  ::: "memory"); break;
    case 6:  asm volatile("s_waitcnt vmcnt(6)"  ::: "memory"); break;
    case 8:  asm volatile("s_waitcnt vmcnt(8)"  ::: "memory"); break;
    default: asm volatile("s_waitcnt vmcnt(10)" ::: "memory"); break;
    }
    __builtin_amdgcn_sched_barrier(0);
}

// fast transcendentals (abs err ~2^-22; validated by R8 absmax 1.5e-5 vs 1e-4 thr)
__device__ __forceinline__ float fast_sig(float x) {
    return 1.0f / (1.0f + __expf(-x));
}
__device__ __forceinline__ float fast_tanh(float x) {
    float xc = fminf(fmaxf(x, -15.0f), 15.0f);
    float e = __expf(2.0f * xc);
    return 1.0f - 2.0f / (e + 1.0f);
}

// ---------------- setup kernels ----------------
__global__ void split_w(const float* __restrict__ src0, int ksplit,
                        const float* __restrict__ src1, int NKT, f16* __restrict__ out)
{
    int c = blockIdx.x * 256 + threadIdx.x;
    int total = 16 * NKT * 2048;
    if (c >= total) return;
    int u = c & 2047;
    int t2 = c >> 11;          // mt*NKT + kt
    int kt = t2 % NKT;
    int mt = t2 / NKT;
    int line = u >> 4;
    int s = (u & 15) ^ (line & 15);   // content slot at this LDS position
    int plane = s >> 3, o = s & 7;
    int m = mt * 128 + line;
    int row = (m & 3) * HD + (m >> 2);    // original row g*512+hl
    int kb = kt * 64 + o * 8;
    f16 v[8];
    #pragma unroll
    for (int e = 0; e < 8; ++e) {
        int k = kb + e;
        float w = (k < ksplit) ? src0[(size_t)row * ksplit + k]
                               : src1[(size_t)row * HD + (k - ksplit)];
        float w32 = w * 32.0f;
        f16 hi = (f16)w32;
        v[e] = plane ? (f16)((w32 - (float)hi) * 2048.0f) : hi;
    }
    *(f16x8*)(out + (size_t)c * 8) = *(f16x8*)v;
}

__global__ void prep_b4(const float* __restrict__ b, float* __restrict__ bt) {
    int c = blockIdx.x * 256 + threadIdx.x;     // c = hl*4+g
    if (c < 2048) bt[c] = b[(c & 3) * HD + (c >> 2)];
}

__global__ void prep_wih4(const float* __restrict__ W, float* __restrict__ o) {
    int c = blockIdx.x * 256 + threadIdx.x;     // c = hl*16 + g*4 + j
    if (c < 8192) {
        int j = c & 3, g = (c >> 2) & 3, hl = c >> 4;
        o[c] = W[(size_t)(g * HD + hl) * 4 + j];
    }
}

// ---------------- cross-block sync: per-block epoch cells (NO RMW) ----------------
__device__ __forceinline__ void publish(int* cell, int epoch) {
    drain_vm();
    __syncthreads();
    if (threadIdx.x == 0)
        coh_store_i32(cell, epoch);
}

__device__ __forceinline__ void wait2(const int* a, int ta, const int* b, int tb) {
    if (threadIdx.x < 64) {
        const int l = threadIdx.x & 15;
        const bool useB = (threadIdx.x & 16) != 0;
        const int* p = (useB ? b : a) + l * 16;
        const int tgt = useB ? tb : ta;
        for (;;) {
            int v = coh_load_i32(p);
            if (__all(v >= tgt)) break;
            __builtin_amdgcn_s_sleep(2);
        }
    }
    __syncthreads();
}

// ---------------- fused LSTM layer-step: depth-4 B / depth-2 A pipeline ----------------
template<int NKT, bool RANK4>
__device__ __forceinline__ void layer_step(
    const f16* __restrict__ Wst, const f16* __restrict__ src1, const f16* __restrict__ src2,
    const float* __restrict__ wih4, const float* __restrict__ xin, int xstride,
    const float* __restrict__ bt4, float* __restrict__ cT, f16* __restrict__ hout,
    char* smem, int mt, int nt)
{
    const int tid = threadIdx.x;
    const int lane = tid & 63;
    const int wv = tid >> 6;            // wave 0..3
    const int wm = wv & 1, wn = wv >> 1;
    const int l15 = lane & 15, j = lane >> 4;
    const int n0 = nt * 64;

    const int q = (j ^ l15) << 4;
    int ALr[4], BLb[2];
    #pragma unroll
    for (int f = 0; f < 4; ++f) ALr[f] = (wm * 64 + f * 16 + l15) * 256;
    #pragma unroll
    for (int fn = 0; fn < 2; ++fn) BLb[fn] = 32768 + (wn * 32 + fn * 16 + l15) * 256;

    float4 rak[2][8];   // A register banks (depth 2)
    float4 rbk[4][4];   // B register banks (depth 4)
    float4 xv[2];

    auto issueA = [&](int kt, int bank) {
        const f16* ga = Wst + ((size_t)mt * NKT + kt) * 2048 * 8;
        #pragma unroll
        for (int i = 0; i < 8; ++i)
            rak[bank][i] = ld_x4(ga + (size_t)(i * 256 + tid) * 8);
    };
    auto issueB = [&](int kt, int bank) {
        #pragma unroll
        for (int i = 0; i < 4; ++i) {
            int v = i * 256 + tid;
            int line = v >> 4;
            int s = (v & 15) ^ (line & 15);
            int ks = kt * 64 + (s & 7) * 8;
            const f16* sp = src1; int kl = ks;
            if (NKT == 16 && ks >= 512) { sp = src2; kl = ks - 512; }
            rbk[bank][i] = coh_ld_x4(sp + (size_t)(n0 + line) * 1024 + (s >> 3) * 512 + kl);
        }
    };

    f32x4 accA[4][2] = {};
    f32x4 accB[4][2] = {};

    // prologue (issue order defines the vmcnt queue — do not reorder)
    if (RANK4) {
        #pragma unroll
        for (int fn = 0; fn < 2; ++fn) {
            const int n = n0 + wn * 32 + fn * 16 + l15;
            xv[fn] = coh_ld_x4(xin + (size_t)n * xstride);
        }
    }
    issueB(0, 0); issueA(0, 0); issueB(1, 1); issueA(1, 1); issueB(2, 2); issueB(3, 3);

    #pragma unroll
    for (int kt = 0; kt < NKT; ++kt) {
        char* buf = smem + (kt & 1) * BUFSZ;
        // instrs newer than needed A(kt) in the queue (derived; see round notes):
        const int wcnt = (kt == NKT - 1) ? 0 : (kt == NKT - 2) ? 8 :
                         (kt == NKT - 3) ? 12 : (kt <= 1) ? 20 : 16;
        wait_vm(wcnt);
        #pragma unroll
        for (int i = 0; i < 8; ++i) *(float4*)(buf + (i * 256 + tid) * 16) = rak[kt & 1][i];
        #pragma unroll
        for (int i = 0; i < 4; ++i) *(float4*)(buf + 32768 + (i * 256 + tid) * 16) = rbk[kt & 3][i];
        if (kt + 2 < NKT) issueA(kt + 2, kt & 1);     // refill bank just consumed
        if (kt + 4 < NKT) issueB(kt + 4, kt & 3);
        __syncthreads();
        #pragma unroll
        for (int i = 0; i < 2; ++i) {
            const int off = (i << 6) ^ q;
            f16x8 ah[4], al[4], bh[2], bl[2];
            #pragma unroll
            for (int f = 0; f < 4; ++f) {
                ah[f] = *(const f16x8*)(buf + ALr[f] + off);
                al[f] = *(const f16x8*)(buf + ALr[f] + (off ^ 0x80));
            }
            #pragma unroll
            for (int fn = 0; fn < 2; ++fn) {
                bh[fn] = *(const f16x8*)(buf + BLb[fn] + off);
                bl[fn] = *(const f16x8*)(buf + BLb[fn] + (off ^ 0x80));
            }
            #pragma unroll
            for (int f = 0; f < 4; ++f)
                #pragma unroll
                for (int fn = 0; fn < 2; ++fn) {
                    accA[f][fn] = __builtin_amdgcn_mfma_f32_16x16x32_f16(ah[f], bh[fn], accA[f][fn], 0, 0, 0);
                    accB[f][fn] = __builtin_amdgcn_mfma_f32_16x16x32_f16(al[f], bh[fn], accB[f][fn], 0, 0, 0);
                    accB[f][fn] = __builtin_amdgcn_mfma_f32_16x16x32_f16(ah[f], bl[fn], accB[f][fn], 0, 0, 0);
                }
        }
    }

    // epilogue: cell update in registers (D regs r=0..3 are gates i,f,g,o of one hl)
    const float sA = 1.0f / 1024.0f;
    const float sB = 1.0f / (1024.0f * 2048.0f);

    uint32_t* htile = (uint32_t*)smem;   // buf0 region; last compute used buf1 (NKT even)
    #pragma unroll
    for (int f = 0; f < 4; ++f) {
        const int hl_loc = wm * 16 + f * 4 + j;
        const int hl = mt * 32 + hl_loc;
        const float4 bv = *(const float4*)(bt4 + hl * 4);
        #pragma unroll
        for (int fn = 0; fn < 2; ++fn) {
            const int n_loc = wn * 32 + fn * 16 + l15;
            const int n = n0 + n_loc;
            float g0 = accA[f][fn][0] * sA + accB[f][fn][0] * sB + bv.x;
            float g1 = accA[f][fn][1] * sA + accB[f][fn][1] * sB + bv.y;
            float g2 = accA[f][fn][2] * sA + accB[f][fn][2] * sB + bv.z;
            float g3 = accA[f][fn][3] * sA + accB[f][fn][3] * sB + bv.w;
            if (RANK4) {
                const float4* wr = (const float4*)(wih4 + hl * 16);
                const float4 x4 = xv[fn];
                g0 += wr[0].x * x4.x + wr[0].y * x4.y + wr[0].z * x4.z + wr[0].w * x4.w;
                g1 += wr[1].x * x4.x + wr[1].y * x4.y + wr[1].z * x4.z + wr[1].w * x4.w;
                g2 += wr[2].x * x4.x + wr[2].y * x4.y + wr[2].z * x4.z + wr[2].w * x4.w;
                g3 += wr[3].x * x4.x + wr[3].y * x4.y + wr[3].z * x4.z + wr[3].w * x4.w;
            }
            const size_t co = (size_t)hl * 1024 + n;   // c: block-private, plain cached
            const float cold = cT[co];
            const float si = fast_sig(g0);
            const float sf = fast_sig(g1);
            const float so = fast_sig(g3);
            const float cn = sf * cold + si * fast_tanh(g2);
            const float hn = so * fast_tanh(cn);
            cT[co] = cn;
            const float h32 = hn * 32.0f;
            const f16 hi = (f16)h32;
            const f16 lo = (f16)((h32 - (float)hi) * 2048.0f);
            uint32_t pk = ((uint32_t)__builtin_bit_cast(uint16_t, lo) << 16)
                        | (uint32_t)__builtin_bit_cast(uint16_t, hi);
            htile[n_loc * 33 + hl_loc] = pk;
        }
    }
    __syncthreads();
    uint32_t* h32out = (uint32_t*)hout;
    #pragma unroll
    for (int i = 0; i < 8; ++i) {
        int u = i * 256 + tid;              // 0..2047
        int n_loc = u >> 5;                 // 0..63
        int r = u & 31;
        int plane = r >> 4;                 // 0=hi, 1=lo
        int p = r & 15;                     // u32 pair index within tile
        uint32_t t0 = htile[n_loc * 33 + 2 * p];
        uint32_t t1 = htile[n_loc * 33 + 2 * p + 1];
        uint32_t w = plane ? ((t1 & 0xffff0000u) | (t0 >> 16))
                           : ((t1 << 16) | (t0 & 0xffffu));
        coh_store_u32(h32out + (size_t)(n0 + n_loc) * 512 + plane * 256 + mt * 16 + p, w);
    }
}

// ---------------- pred + softmax, 4 batch rows per block (wave w -> row w) ----------------
__device__ __forceinline__ void pred_step(
    const f16* __restrict__ h1, const float* __restrict__ Wp, const float* __restrict__ bp,
    float* __restrict__ outp, float* __restrict__ xfb, int t, int mt, int nt)
{
    const int lane = threadIdx.x & 63;
    const int wv = threadIdx.x >> 6;
    const int n = nt * 64 + mt * 4 + wv;
    const f16* hr = h1 + (size_t)n * 1024;
    const int k0 = lane * 8;
    float4 hv4 = coh_ld_x4(hr + k0);
    float4 lv4 = coh_ld_x4(hr + 512 + k0);
    drain_vm();
    f16x8 hv = __builtin_bit_cast(f16x8, hv4);
    f16x8 lv = __builtin_bit_cast(f16x8, lv4);
    float h[8];
    #pragma unroll
    for (int e = 0; e < 8; ++e)
        h[e] = (float)hv[e] * 0.03125f + (float)lv[e] * (1.0f / 65536.0f);
    float a[4] = {};
    #pragma unroll
    for (int g = 0; g < 4; ++g) {
        const float4 wa = *(const float4*)(Wp + g * HD + k0);
        const float4 wb = *(const float4*)(Wp + g * HD + k0 + 4);
        a[g] = h[0]*wa.x + h[1]*wa.y + h[2]*wa.z + h[3]*wa.w
             + h[4]*wb.x + h[5]*wb.y + h[6]*wb.z + h[7]*wb.w;
    }
    #pragma unroll
    for (int off = 32; off > 0; off >>= 1) {
        a[0] += __shfl_xor(a[0], off);
        a[1] += __shfl_xor(a[1], off);
        a[2] += __shfl_xor(a[2], off);
        a[3] += __shfl_xor(a[3], off);
    }
    if (lane == 0) {
        const float4 bv = *(const float4*)bp;
        float v0 = a[0] + bv.x, v1 = a[1] + bv.y, v2 = a[2] + bv.z, v3 = a[3] + bv.w;
        float* op = outp + (size_t)n * (TST * 4) + t * 4;
        op[0] = v0; op[1] = v1; op[2] = v2; op[3] = v3;
        float m = fmaxf(fmaxf(v0, v1), fmaxf(v2, v3));
        float e0 = expf(v0 - m), e1 = expf(v1 - m), e2 = expf(v2 - m), e3 = expf(v3 - m);
        float inv = 1.0f / (e0 + e1 + e2 + e3);
        uint32_t* xp = (uint32_t*)(xfb + n * 4);
        float s0 = e0 * inv, s1 = e1 * inv, s2 = e2 * inv, s3 = e3 * inv;
        coh_store_u32(xp + 0, __builtin_bit_cast(uint32_t, s0));
        coh_store_u32(xp + 1, __builtin_bit_cast(uint32_t, s1));
        coh_store_u32(xp + 2, __builtin_bit_cast(uint32_t, s2));
        coh_store_u32(xp + 3, __builtin_bit_cast(uint32_t, s3));
    }
}

// ---------------- persistent whole-network kernel ----------------
struct Params {
    const f16 *WE0, *WE1, *WD0, *WD1;
    const float *wih4E, *wih4D, *btE0, *btE1, *btD0, *btD1;
    const float *X, *Wp, *bp;
    f16 *h0a, *h0b, *h1a, *h1b;
    float *c0, *c1;
    float *xfb0, *xfb1;
    float *out;
    int *f0, *f1, *fp;   // per-block epoch cells: [16 groups][16 blocks x 16 ints]
};

__launch_bounds__(256, 1) __global__ void lstm_persistent(Params P)
{
    __shared__ __align__(16) char smem[2 * BUFSZ];
    const int bx = blockIdx.x;
    const int mt = ((bx & 7) << 1) | ((bx >> 3) & 1);  // 0..15 (weights L2-resident per XCD)
    const int nt = bx >> 4;                            // 0..15 (batch-column group)
    int* f0g = P.f0 + nt * 256;
    int* f1g = P.f1 + nt * 256;
    int* fpg = P.fp + nt * 256;
    int* my0 = f0g + mt * 16;
    int* my1 = f1g + mt * 16;
    int* myp = fpg + mt * 16;
    f16* h0b_[2] = { P.h0a, P.h0b };
    f16* h1b_[2] = { P.h1a, P.h1b };
    float* xfb_[2] = { P.xfb0, P.xfb1 };

    for (int u = 0; u < 2 * TST; ++u) {
        const bool enc = (u < TST);
        const int t = enc ? u : u - TST;

        // ---- layer 0 ---- (f0 >= u: group's l0(u-1) done; WAR-safe by program order)
        if (enc) wait2(f0g, u, f0g, u);
        else     wait2(f0g, u, fpg, t);    // + xfb(t-1) ready
        layer_step<8, true>(enc ? P.WE0 : P.WD0,
                            h0b_[(u + 1) & 1], nullptr,
                            enc ? P.wih4E : P.wih4D,
                            enc ? (P.X + t * 4) : xfb_[(t + 1) & 1],
                            enc ? (TST * 4) : 4,
                            enc ? P.btE0 : P.btD0,
                            P.c0, h0b_[u & 1], smem, mt, nt);
        publish(my0, u + 1);

        // ---- layer 1 ---- (h0(u) ready AND h1(u-1) ready)
        wait2(f0g, u + 1, f1g, u);
        layer_step<16, false>(enc ? P.WE1 : P.WD1,
                              h0b_[u & 1], h1b_[(u + 1) & 1],
                              nullptr, nullptr, 0,
                              enc ? P.btE1 : P.btD1,
                              P.c1, h1b_[u & 1], smem, mt, nt);
        publish(my1, u + 1);

        // ---- pred + softmax feedback (decoder only) ----
        if (!enc) {
            wait2(f1g, u + 1, f1g, u + 1);   // full h1(t) rows from group
            pred_step(h1b_[u & 1], P.Wp, P.bp, P.out, xfb_[t & 1], t, mt, nt);
            publish(myp, t + 1);
        }
    }
}

// ---------------- host ----------------
extern "C" void kernel_launch(void* const* d_in, const int* in_sizes, int n_in,
                              void* d_out, int out_size, void* d_ws, size_t ws_size,
                              hipStream_t stream)
{
    const float* X     = (const float*)d_in[0];
    const float* eWih0 = (const float*)d_in[2];
    const float* eWhh0 = (const float*)d_in[3];
    const float* eb0   = (const float*)d_in[4];
    const float* eWih1 = (const float*)d_in[5];
    const float* eWhh1 = (const float*)d_in[6];
    const float* eb1   = (const float*)d_in[7];
    const float* dWih0 = (const float*)d_in[8];
    const float* dWhh0 = (const float*)d_in[9];
    const float* db0   = (const float*)d_in[10];
    const float* dWih1 = (const float*)d_in[11];
    const float* dWhh1 = (const float*)d_in[12];
    const float* db1   = (const float*)d_in[13];
    const float* Wp    = (const float*)d_in[14];
    const float* bp    = (const float*)d_in[15];

    char* ws = (char*)d_ws;
    size_t off = 0;
    auto alloc = [&](size_t bytes) { char* p = ws + off; off += (bytes + 255) & ~(size_t)255; return p; };
    f16* WE0 = (f16*)alloc((size_t)16 * 8  * 32768);
    f16* WE1 = (f16*)alloc((size_t)16 * 16 * 32768);
    f16* WD0 = (f16*)alloc((size_t)16 * 8  * 32768);
    f16* WD1 = (f16*)alloc((size_t)16 * 16 * 32768);
    float* wih4E = (float*)alloc(8192 * 4);
    float* wih4D = (float*)alloc(8192 * 4);
    float* btE0 = (float*)alloc(2048 * 4);
    float* btE1 = (float*)alloc(2048 * 4);
    float* btD0 = (float*)alloc(2048 * 4);
    float* btD1 = (float*)alloc(2048 * 4);
    f16* h0a = (f16*)alloc((size_t)BATCH * 1024 * 2);
    f16* h0b = (f16*)alloc((size_t)BATCH * 1024 * 2);
    f16* h1a = (f16*)alloc((size_t)BATCH * 1024 * 2);
    f16* h1b = (f16*)alloc((size_t)BATCH * 1024 * 2);
    float* c0  = (float*)alloc((size_t)HD * BATCH * 4);
    float* c1  = (float*)alloc((size_t)HD * BATCH * 4);
    float* xfb0 = (float*)alloc((size_t)BATCH * 4 * 4);
    float* xfb1 = (float*)alloc((size_t)BATCH * 4 * 4);
    int* f0 = (int*)alloc(16 * 256 * 4);
    int* f1 = (int*)alloc(16 * 256 * 4);
    int* fp = (int*)alloc(16 * 256 * 4);
    if (off > ws_size) return;   // workspace too small -> loud failure

    // one-time (per-call) weight prep
    split_w<<<(16 * 8  * 2048) / 256, 256, 0, stream>>>(nullptr, 0,   eWhh0, 8,  WE0);
    split_w<<<(16 * 16 * 2048) / 256, 256, 0, stream>>>(eWih1, 512, eWhh1, 16, WE1);
    split_w<<<(16 * 8  * 2048) / 256, 256, 0, stream>>>(nullptr, 0,   dWhh0, 8,  WD0);
    split_w<<<(16 * 16 * 2048) / 256, 256, 0, stream>>>(dWih1, 512, dWhh1, 16, WD1);
    prep_wih4<<<32, 256, 0, stream>>>(eWih0, wih4E);
    prep_wih4<<<32, 256, 0, stream>>>(dWih0, wih4D);
    prep_b4<<<8, 256, 0, stream>>>(eb0, btE0);
    prep_b4<<<8, 256, 0, stream>>>(eb1, btE1);
    prep_b4<<<8, 256, 0, stream>>>(db0, btD0);
    prep_b4<<<8, 256, 0, stream>>>(db1, btD1);

    hipMemsetAsync(h0b, 0, (size_t)BATCH * 1024 * 2, stream);   // h0 parity-1 (read at u=0)
    hipMemsetAsync(h1b, 0, (size_t)BATCH * 1024 * 2, stream);   // h1 parity-1
    hipMemsetAsync(c0, 0, (size_t)HD * BATCH * 4, stream);
    hipMemsetAsync(c1, 0, (size_t)HD * BATCH * 4, stream);
    hipMemsetAsync(xfb1, 0, (size_t)BATCH * 4 * 4, stream);     // x feedback at dec t=0
    hipMemsetAsync(f0, 0, 16 * 256 * 4, stream);
    hipMemsetAsync(f1, 0, 16 * 256 * 4, stream);
    hipMemsetAsync(fp, 0, 16 * 256 * 4, stream);

    Params P;
    P.WE0 = WE0; P.WE1 = WE1; P.WD0 = WD0; P.WD1 = WD1;
    P.wih4E = wih4E; P.wih4D = wih4D;
    P.btE0 = btE0; P.btE1 = btE1; P.btD0 = btD0; P.btD1 = btD1;
    P.X = X; P.Wp = Wp; P.bp = bp;
    P.h0a = h0a; P.h0b = h0b; P.h1a = h1a; P.h1b = h1b;
    P.c0 = c0; P.c1 = c1;
    P.xfb0 = xfb0; P.xfb1 = xfb1;
    P.out = (float*)d_out;
    P.f0 = f0; P.f1 = f1; P.fp = fp;

    lstm_persistent<<<256, 256, 0, stream>>>(P);

    (void)in_sizes; (void)n_in; (void)out_size;
}